// Round 1
// baseline (146839.490 us; speedup 1.0000x reference)
//
#include <hip/hip_runtime.h>
#include <hip/hip_bf16.h>
#include <hip/hip_fp16.h>

// Persistent dataflow RNN for MI355X.
//   SEQ=4096, HID=2048, 4 layers. 256 WGs (1/CU), 64 per layer, 32 rows each.
//   Weights held in VGPRs as fp16 MFMA A-fragments (64 VGPRs/lane).
//   Cross-WG sync: per-WG monotonic step counters, agent-scope release/acquire.

#define SEQ 4096
#define HID 2048
#define NL 4
#define WGS_PER_LAYER 64
#define ROWS_PER_WG 32
#define KCAT 4096      // concat(x, h)
#define NTILE 16       // 16 MFMAs (k=32 each) per wave per step: 512 k per wave

typedef _Float16 f16x8 __attribute__((ext_vector_type(8)));
typedef float f32x4 __attribute__((ext_vector_type(4)));

// Static device buffers (avoid ws_size assumptions). Re-initialized every call.
__device__ __align__(16) _Float16 g_xin[(size_t)SEQ * HID];        // 16 MB
__device__ __align__(16) _Float16 g_ring[NL][SEQ][HID];            // 67 MB history
__device__ int g_flags[NL][WGS_PER_LAYER];                         // steps completed

__global__ void prep_kernel(const float* __restrict__ x) {
  size_t i = (size_t)blockIdx.x * blockDim.x + threadIdx.x;
  if (blockIdx.x == 0 && threadIdx.x < NL * WGS_PER_LAYER)
    ((int*)g_flags)[threadIdx.x] = 0;
  if (i < (size_t)SEQ * HID) g_xin[i] = (_Float16)x[i];
}

__global__ __launch_bounds__(1024) void rnn_kernel(
    const float* __restrict__ wih, const float* __restrict__ whh,
    float* __restrict__ out) {
  const int layer = blockIdx.x & 3;   // interleave layers across XCD round-robin
  const int wg    = blockIdx.x >> 2;  // 0..63 within layer
  const int tid   = threadIdx.x;
  const int lane  = tid & 63;
  const int wave  = tid >> 6;         // 16 waves
  const int rb    = wave & 1;         // row block (16 rows each)
  const int kr    = wave >> 1;        // k range 0..7 (512 k each)
  const int m     = lane & 15;
  const int q     = lane >> 4;
  const int row   = wg * ROWS_PER_WG + rb * 16 + m;  // weight row this lane holds

  __shared__ __align__(16) _Float16 cat[KCAT];       // [0,2048)=x_t  [2048,4096)=h_{t-1}
  __shared__ __align__(16) float partials[16][16];   // [kr*2+rb][row within 32.. as 2x16]

  // ---- one-time: weights -> registers as fp16 A-fragments ----
  // A layout (16x16x32): lane holds A[m = lane&15][k = ktile + q*8 + j], j=0..7
  f16x8 afrag[NTILE];
  {
    const float* wl = wih + (size_t)layer * HID * HID + (size_t)row * HID;
    const float* wr = whh + (size_t)layer * HID * HID + (size_t)row * HID - HID;
#pragma unroll
    for (int i = 0; i < NTILE; ++i) {
      int kabs = kr * 512 + i * 32 + q * 8;          // multiple of 8; tiles never straddle 2048
      const float* src = (kabs < HID) ? (wl + kabs) : (wr + kabs);
      f32x4 w0 = *(const f32x4*)(src);
      f32x4 w1 = *(const f32x4*)(src + 4);
      f16x8 a;
      a[0] = (_Float16)w0[0]; a[1] = (_Float16)w0[1];
      a[2] = (_Float16)w0[2]; a[3] = (_Float16)w0[3];
      a[4] = (_Float16)w1[0]; a[5] = (_Float16)w1[1];
      a[6] = (_Float16)w1[2]; a[7] = (_Float16)w1[3];
      afrag[i] = a;
    }
  }

  bool bailed = false;  // safety: never hang the harness

  for (int t = 0; t < SEQ; ++t) {
    // ---- wait for own h_{t-1} (all 64 WGs >= t) and prev layer x_t (>= t+1) ----
    if (tid < 64 && !bailed) {
      int spin = 0;
      for (;;) {
        int fo = __hip_atomic_load(&g_flags[layer][lane], __ATOMIC_RELAXED,
                                   __HIP_MEMORY_SCOPE_AGENT);
        bool ok = (fo >= t);
        if (layer > 0) {
          int fp = __hip_atomic_load(&g_flags[layer - 1][lane], __ATOMIC_RELAXED,
                                     __HIP_MEMORY_SCOPE_AGENT);
          ok = ok && (fp >= t + 1);
        }
        if (__ballot(ok) == ~0ull) break;
        if (++spin > (1 << 22)) { bailed = true; break; }
        __builtin_amdgcn_s_sleep(1);
      }
    }
    __syncthreads();
    __builtin_amdgcn_fence(__ATOMIC_ACQUIRE, "agent");  // all threads: inv stale caches

    // ---- stage concat(x_t, h_{t-1}) into LDS: 8 KB, one uint2 per thread ----
    if (tid < 512) {
      const uint2* src = (layer == 0)
          ? (const uint2*)(g_xin + (size_t)t * HID)
          : (const uint2*)(&g_ring[layer - 1][t][0]);
      ((uint2*)cat)[tid] = src[tid];
    } else {
      uint2 v = make_uint2(0u, 0u);
      if (t > 0) v = ((const uint2*)(&g_ring[layer][t - 1][0]))[tid - 512];
      ((uint2*)cat)[tid] = v;
    }
    __syncthreads();

    // ---- MFMA: rows (16) x own k-range (512). B = h broadcast to all 16 cols ----
    f32x4 acc0 = {0.f, 0.f, 0.f, 0.f}, acc1 = {0.f, 0.f, 0.f, 0.f};
    const f16x8* bb = (const f16x8*)cat;  // 16B units
#pragma unroll
    for (int i = 0; i < NTILE; i += 2) {
      f16x8 b0 = bb[kr * 64 + i * 4 + q];
      f16x8 b1 = bb[kr * 64 + (i + 1) * 4 + q];
      acc0 = __builtin_amdgcn_mfma_f32_16x16x32_f16(afrag[i], b0, acc0, 0, 0, 0);
      acc1 = __builtin_amdgcn_mfma_f32_16x16x32_f16(afrag[i + 1], b1, acc1, 0, 0, 0);
    }
    f32x4 accs = acc0 + acc1;
    // D layout: col=lane&15 (all cols equal here), row=(lane>>4)*4+reg
    if (m == 0) *(f32x4*)&partials[kr * 2 + rb][q * 4] = accs;
    __syncthreads();

    // ---- reduce 8 k-partials per row, relu, publish ----
    if (tid < ROWS_PER_WG) {
      int rbb = tid >> 4, rr = tid & 15;
      float s = 0.f;
#pragma unroll
      for (int k = 0; k < 8; ++k) s += partials[k * 2 + rbb][rr];
      s = fmaxf(s, 0.f);
      int gr = wg * ROWS_PER_WG + tid;
      g_ring[layer][t][gr] = (_Float16)s;
      if (layer == NL - 1) {
        out[(size_t)t * HID + gr] = s;                       // output[0, t, :]
        if (t == SEQ - 1) out[(size_t)SEQ * HID + gr] = s;   // h_last
      }
    }
    __syncthreads();  // drains vmcnt: slice stores complete before flag release

    if (tid == 0)
      __hip_atomic_store(&g_flags[layer][wg], t + 1, __ATOMIC_RELEASE,
                         __HIP_MEMORY_SCOPE_AGENT);
  }
}

extern "C" void kernel_launch(void* const* d_in, const int* in_sizes, int n_in,
                              void* d_out, int out_size, void* d_ws, size_t ws_size,
                              hipStream_t stream) {
  const float* x   = (const float*)d_in[0];
  const float* wih = (const float*)d_in[1];
  const float* whh = (const float*)d_in[2];
  float* out = (float*)d_out;

  prep_kernel<<<(SEQ * HID + 1023) / 1024, 1024, 0, stream>>>(x);
  rnn_kernel<<<NL * WGS_PER_LAYER, 1024, 0, stream>>>(wih, whh, out);
}

// Round 2
// 146675.610 us; speedup vs baseline: 1.0011x; 1.0011x over previous
//
#include <hip/hip_runtime.h>
#include <hip/hip_bf16.h>
#include <hip/hip_fp16.h>

// Persistent dataflow RNN for MI355X.
//   SEQ=4096, HID=2048, 4 layers. 256 WGs (1/CU), 64 per layer, 32 rows each.
//   Weights held in VGPRs as fp16 MFMA A-fragments (64 VGPRs/lane).
//   Cross-WG sync: per-WG monotonic step counters, agent-scope release/acquire.
//
// R2 change: __launch_bounds__(1024, 4) — 4 waves/EU = exactly one 16-wave
// block per CU, raising the VGPR cap 64 -> 128 so the 64-VGPR weight-fragment
// array stays register-resident. R1's implicit cap (targeting 2 blocks/CU)
// made the compiler sink weight loads into the t-loop: 300 GB of HBM fetch.

#define SEQ 4096
#define HID 2048
#define NL 4
#define WGS_PER_LAYER 64
#define ROWS_PER_WG 32
#define KCAT 4096      // concat(x, h)
#define NTILE 16       // 16 MFMAs (k=32 each) per wave per step: 512 k per wave

typedef _Float16 f16x8 __attribute__((ext_vector_type(8)));
typedef float f32x4 __attribute__((ext_vector_type(4)));

// Static device buffers (avoid ws_size assumptions). Re-initialized every call.
__device__ __align__(16) _Float16 g_xin[(size_t)SEQ * HID];        // 16 MB
__device__ __align__(16) _Float16 g_ring[NL][SEQ][HID];            // 67 MB history
__device__ int g_flags[NL][WGS_PER_LAYER];                         // steps completed

__global__ void prep_kernel(const float* __restrict__ x) {
  size_t i = (size_t)blockIdx.x * blockDim.x + threadIdx.x;
  if (blockIdx.x == 0 && threadIdx.x < NL * WGS_PER_LAYER)
    ((int*)g_flags)[threadIdx.x] = 0;
  if (i < (size_t)SEQ * HID) g_xin[i] = (_Float16)x[i];
}

__global__ __launch_bounds__(1024, 4) void rnn_kernel(
    const float* __restrict__ wih, const float* __restrict__ whh,
    float* __restrict__ out) {
  const int layer = blockIdx.x & 3;   // interleave layers across XCD round-robin
  const int wg    = blockIdx.x >> 2;  // 0..63 within layer
  const int tid   = threadIdx.x;
  const int lane  = tid & 63;
  const int wave  = tid >> 6;         // 16 waves
  const int rb    = wave & 1;         // row block (16 rows each)
  const int kr    = wave >> 1;        // k range 0..7 (512 k each)
  const int m     = lane & 15;
  const int q     = lane >> 4;
  const int row   = wg * ROWS_PER_WG + rb * 16 + m;  // weight row this lane holds

  __shared__ __align__(16) _Float16 cat[KCAT];       // [0,2048)=x_t  [2048,4096)=h_{t-1}
  __shared__ __align__(16) float partials[16][16];   // [kr*2+rb][row within 32.. as 2x16]

  // ---- one-time: weights -> registers as fp16 A-fragments ----
  // A layout (16x16x32): lane holds A[m = lane&15][k = ktile + q*8 + j], j=0..7
  f16x8 afrag[NTILE];
  {
    const float* wl = wih + (size_t)layer * HID * HID + (size_t)row * HID;
    const float* wr = whh + (size_t)layer * HID * HID + (size_t)row * HID - HID;
#pragma unroll
    for (int i = 0; i < NTILE; ++i) {
      int kabs = kr * 512 + i * 32 + q * 8;          // multiple of 8; tiles never straddle 2048
      const float* src = (kabs < HID) ? (wl + kabs) : (wr + kabs);
      f32x4 w0 = *(const f32x4*)(src);
      f32x4 w1 = *(const f32x4*)(src + 4);
      f16x8 a;
      a[0] = (_Float16)w0[0]; a[1] = (_Float16)w0[1];
      a[2] = (_Float16)w0[2]; a[3] = (_Float16)w0[3];
      a[4] = (_Float16)w1[0]; a[5] = (_Float16)w1[1];
      a[6] = (_Float16)w1[2]; a[7] = (_Float16)w1[3];
      afrag[i] = a;
    }
  }

  bool bailed = false;  // safety: never hang the harness

  for (int t = 0; t < SEQ; ++t) {
    // ---- wait for own h_{t-1} (all 64 WGs >= t) and prev layer x_t (>= t+1) ----
    if (tid < 64 && !bailed) {
      int spin = 0;
      for (;;) {
        int fo = __hip_atomic_load(&g_flags[layer][lane], __ATOMIC_RELAXED,
                                   __HIP_MEMORY_SCOPE_AGENT);
        bool ok = (fo >= t);
        if (layer > 0) {
          int fp = __hip_atomic_load(&g_flags[layer - 1][lane], __ATOMIC_RELAXED,
                                     __HIP_MEMORY_SCOPE_AGENT);
          ok = ok && (fp >= t + 1);
        }
        if (__ballot(ok) == ~0ull) break;
        if (++spin > (1 << 22)) { bailed = true; break; }
        __builtin_amdgcn_s_sleep(1);
      }
    }
    __syncthreads();
    __builtin_amdgcn_fence(__ATOMIC_ACQUIRE, "agent");  // all threads: inv stale caches

    // ---- stage concat(x_t, h_{t-1}) into LDS: 8 KB, one uint2 per thread ----
    if (tid < 512) {
      const uint2* src = (layer == 0)
          ? (const uint2*)(g_xin + (size_t)t * HID)
          : (const uint2*)(&g_ring[layer - 1][t][0]);
      ((uint2*)cat)[tid] = src[tid];
    } else {
      uint2 v = make_uint2(0u, 0u);
      if (t > 0) v = ((const uint2*)(&g_ring[layer][t - 1][0]))[tid - 512];
      ((uint2*)cat)[tid] = v;
    }
    __syncthreads();

    // ---- MFMA: rows (16) x own k-range (512). B = h broadcast to all 16 cols ----
    f32x4 acc0 = {0.f, 0.f, 0.f, 0.f}, acc1 = {0.f, 0.f, 0.f, 0.f};
    const f16x8* bb = (const f16x8*)cat;  // 16B units
#pragma unroll
    for (int i = 0; i < NTILE; i += 2) {
      f16x8 b0 = bb[kr * 64 + i * 4 + q];
      f16x8 b1 = bb[kr * 64 + (i + 1) * 4 + q];
      acc0 = __builtin_amdgcn_mfma_f32_16x16x32_f16(afrag[i], b0, acc0, 0, 0, 0);
      acc1 = __builtin_amdgcn_mfma_f32_16x16x32_f16(afrag[i + 1], b1, acc1, 0, 0, 0);
    }
    f32x4 accs = acc0 + acc1;
    // D layout: col=lane&15 (all cols equal here), row=(lane>>4)*4+reg
    if (m == 0) *(f32x4*)&partials[kr * 2 + rb][q * 4] = accs;
    __syncthreads();

    // ---- reduce 8 k-partials per row, relu, publish ----
    if (tid < ROWS_PER_WG) {
      int rbb = tid >> 4, rr = tid & 15;
      float s = 0.f;
#pragma unroll
      for (int k = 0; k < 8; ++k) s += partials[k * 2 + rbb][rr];
      s = fmaxf(s, 0.f);
      int gr = wg * ROWS_PER_WG + tid;
      g_ring[layer][t][gr] = (_Float16)s;
      if (layer == NL - 1) {
        out[(size_t)t * HID + gr] = s;                       // output[0, t, :]
        if (t == SEQ - 1) out[(size_t)SEQ * HID + gr] = s;   // h_last
      }
    }
    __syncthreads();  // drains vmcnt: slice stores complete before flag release

    if (tid == 0)
      __hip_atomic_store(&g_flags[layer][wg], t + 1, __ATOMIC_RELEASE,
                         __HIP_MEMORY_SCOPE_AGENT);
  }
}

extern "C" void kernel_launch(void* const* d_in, const int* in_sizes, int n_in,
                              void* d_out, int out_size, void* d_ws, size_t ws_size,
                              hipStream_t stream) {
  const float* x   = (const float*)d_in[0];
  const float* wih = (const float*)d_in[1];
  const float* whh = (const float*)d_in[2];
  float* out = (float*)d_out;

  prep_kernel<<<(SEQ * HID + 1023) / 1024, 1024, 0, stream>>>(x);
  rnn_kernel<<<NL * WGS_PER_LAYER, 1024, 0, stream>>>(wih, whh, out);
}